// Round 6
// baseline (50.078 us; speedup 1.0000x reference)
//
#include <hip/hip_runtime.h>
#include <math.h>

constexpr int B_   = 8;
constexpr int N_   = 2048;
constexpr int D_   = 32;
constexpr int PIN  = 8;
constexpr int POUT = 4;
constexpr int COLS = 128;      // D_*POUT
constexpr int BM   = 32;       // GEMM row tile
constexpr int BK   = 64;       // GEMM k tile
constexpr int NT   = N_ / BK;  // 32 k-steps

using f32x4  = __attribute__((ext_vector_type(4))) float;
using bf16x8 = __attribute__((ext_vector_type(8))) short;

__device__ __forceinline__ unsigned short f2bf(float f) {
    union { float f; unsigned u; } v; v.f = f;
    unsigned u = v.u + 0x7fffu + ((v.u >> 16) & 1u);   // RTNE
    return (unsigned short)(u >> 16);
}

// 16B global->LDS DMA. LDS dest is wave-uniform base + lane*16 (m104/m108).
__device__ __forceinline__ void dma16(const void* g, void* l) {
    __builtin_amdgcn_global_load_lds(
        (const __attribute__((address_space(1))) unsigned int*)g,
        (__attribute__((address_space(3))) unsigned int*)(uintptr_t)l,
        16, 0, 0);
}

// ---- kernel T: Btg[b][col=4d+o][n] = bf16(U@Wn); Mself[b][n][4d+o] = U@Ws ----
__global__ __launch_bounds__(256) void mneigh_t_kernel(
    const float* __restrict__ U, const float* __restrict__ Wn,
    const float* __restrict__ Ws, unsigned short* __restrict__ Btg,
    float* __restrict__ Mself)
{
    const int bt = blockIdx.x;       // 512 blocks
    const int b  = bt >> 6;          // batch
    const int n0 = (bt & 63) * 32;   // 32 n-rows per block
    const int t  = threadIdx.x;
    const int d  = t >> 3;           // 0..31
    const int ns = t & 7;            // 0..7 -> rows n0+ns*4 .. +3

    float wn[PIN][POUT], ws[PIN][POUT];
#pragma unroll
    for (int p = 0; p < PIN; ++p)
#pragma unroll
        for (int o = 0; o < POUT; ++o) {
            wn[p][o] = Wn[p * POUT + o];
            ws[p][o] = Ws[p * POUT + o];
        }

    union { unsigned short s[4]; int2 v; } ob[POUT];
    const float* Ub = U + (((size_t)(b * N_ + n0 + ns * 4)) * D_ + d) * PIN;
#pragma unroll
    for (int ni = 0; ni < 4; ++ni) {
        const float4 u0 = *(const float4*)(Ub + (size_t)ni * D_ * PIN);
        const float4 u1 = *(const float4*)(Ub + (size_t)ni * D_ * PIN + 4);
        const float uu[8] = {u0.x, u0.y, u0.z, u0.w, u1.x, u1.y, u1.z, u1.w};
        float4 ms;
#pragma unroll
        for (int o = 0; o < POUT; ++o) {
            float sn = 0.f, ss = 0.f;
#pragma unroll
            for (int p = 0; p < PIN; ++p) {
                sn = fmaf(uu[p], wn[p][o], sn);
                ss = fmaf(uu[p], ws[p][o], ss);
            }
            ob[o].s[ni] = f2bf(sn);
            ((float*)&ms)[o] = ss;
        }
        *(float4*)(Mself + ((size_t)(b * N_ + n0 + ns * 4 + ni)) * COLS + d * 4) = ms;
    }
#pragma unroll
    for (int o = 0; o < POUT; ++o) {
        unsigned short* dst =
            Btg + ((size_t)(b * COLS + d * 4 + o)) * N_ + n0 + ns * 4;
        *(int2*)dst = ob[o].v;
    }
}

// ---- kernel G: M_agg = A @ Mneigh (bf16 MFMA); Y=relu(+Mself+bias); polar ----
// global_load_lds staging (unsinkable), counted vmcnt(3), dbuf, 2 barriers/tile.
__global__ __launch_bounds__(512) void gemm_proj_kernel(
    const float* __restrict__ A, const unsigned short* __restrict__ Btg,
    const float* __restrict__ Mself, const float* __restrict__ bias,
    float* __restrict__ out)
{
    __shared__ unsigned char smem[49152];
    // staging: A f32 [32][64] dbuf @0 (2x8KB); B bf16 [128][64] dbuf @16384 (2x16KB)
    // epilogue reuse: Yl f32 [32][132] @0; Gp @16896; Sm @22016
    float* Yl = (float*)smem;
    float* Gp = (float*)(smem + 16896);
    float* Sm = (float*)(smem + 22016);

    // T1: bijective XCD swizzle (512 % 8 == 0): XCD x owns batch x.
    const int bid = (blockIdx.x & 7) * 64 + (blockIdx.x >> 3);
    const int b   = bid >> 6;
    const int r0  = (bid & 63) * BM;
    const int t   = threadIdx.x;
    const int lane = t & 63, wv = t >> 6;
    const int wr = wv >> 2, wc = wv & 3;       // wave -> 16-row x 32-col subtile
    const int q = lane >> 4, rl = lane & 15;
    const unsigned swzA = (unsigned)((lane & 7) << 5);  // f32 rows, 32B granule
    const unsigned swzB = (unsigned)((lane & 7) << 4);  // bf16 rows, 16B granule
    const int rA = wr * 16 + rl;

    const char* Ab = (const char*)(A + (size_t)b * N_ * N_ + (size_t)r0 * N_);
    const char* Bb = (const char*)(Btg + (size_t)b * COLS * N_);

    // DMA per-lane global sources (pre-swizzled: LDS dest stays linear)
    const int arow = t >> 4;   // A: 1 DMA/thread, row=t>>4, slot=t&15
    const unsigned ainner =
        ((unsigned)((t & 15) * 16)) ^ ((unsigned)((arow & 7) << 5));
    const char* a_src = Ab + (size_t)arow * (N_ * 4) + ainner;
    const int bcol = t >> 3;   // B: 2 DMA/thread, cols bcol and bcol+64
    const unsigned binner =
        ((unsigned)((t & 7) * 16)) ^ ((unsigned)((bcol & 7) << 4));
    const char* b_src0 = Bb + (size_t)bcol * (N_ * 2) + binner;
    const char* b_src1 = Bb + (size_t)(bcol + 64) * (N_ * 2) + binner;

    // wave-uniform LDS dest bases (HW adds lane*16)
    unsigned char* a_dst = smem + wv * 1024;           // + buf*8192
    unsigned char* b_dst = smem + 16384 + wv * 1024;   // + buf*16384 (+8192 hi)

#define STAGE(K0, BUF)                                                   \
    do {                                                                 \
        dma16(a_src + (size_t)(K0) * 4, a_dst + (BUF) * 8192);           \
        dma16(b_src0 + (size_t)(K0) * 2, b_dst + (BUF) * 16384);         \
        dma16(b_src1 + (size_t)(K0) * 2, b_dst + (BUF) * 16384 + 8192);  \
    } while (0)

    f32x4 acc[2] = {f32x4{0, 0, 0, 0}, f32x4{0, 0, 0, 0}};

    STAGE(0, 0);
    STAGE(BK, 1);
    asm volatile("s_waitcnt vmcnt(3)" ::: "memory");   // tile0 landed
    __builtin_amdgcn_s_barrier();

    for (int kt = 0; kt < NT; ++kt) {
        const unsigned cur = (unsigned)(kt & 1);
        const unsigned abase = cur * 8192u;
        const unsigned bbase = 16384u + cur * 16384u;
        __builtin_amdgcn_s_setprio(1);
#pragma unroll
        for (int ks = 0; ks < 2; ++ks) {
            const unsigned aoff = ((unsigned)(ks * 128 + q * 32)) ^ swzA;
            const float4 alo =
                *(const float4*)(smem + abase + rA * 256 + aoff);
            const float4 ahi =
                *(const float4*)(smem + abase + rA * 256 + aoff + 16);
            union { unsigned u[4]; bf16x8 v; } af;
            asm("v_cvt_pk_bf16_f32 %0, %1, %2"
                : "=v"(af.u[0]) : "v"(alo.x), "v"(alo.y));
            asm("v_cvt_pk_bf16_f32 %0, %1, %2"
                : "=v"(af.u[1]) : "v"(alo.z), "v"(alo.w));
            asm("v_cvt_pk_bf16_f32 %0, %1, %2"
                : "=v"(af.u[2]) : "v"(ahi.x), "v"(ahi.y));
            asm("v_cvt_pk_bf16_f32 %0, %1, %2"
                : "=v"(af.u[3]) : "v"(ahi.z), "v"(ahi.w));
#pragma unroll
            for (int cf = 0; cf < 2; ++cf) {
                const int rB = wc * 32 + cf * 16 + rl;
                const bf16x8 bfr = *(const bf16x8*)(
                    smem + bbase + rB * 128 +
                    (((unsigned)(ks * 64 + q * 16)) ^ swzB));
                acc[cf] = __builtin_amdgcn_mfma_f32_16x16x32_bf16(
                    af.v, bfr, acc[cf], 0, 0, 0);
            }
        }
        __builtin_amdgcn_s_setprio(0);
        __builtin_amdgcn_s_barrier();   // all waves done reading buf[cur]
        const int k2 = (kt + 2 < NT) ? (kt + 2) * BK : 0;   // wrap: harmless restage
        STAGE(k2, cur);
        asm volatile("s_waitcnt vmcnt(3)" ::: "memory");    // tile kt+1 landed
        __builtin_amdgcn_s_barrier();
    }
#undef STAGE
    __syncthreads();   // full drain (incl. trailing DMA) before smem reuse

    // ---- epilogue ----
    // 1) M_agg -> Yl   (C/D map: col=lane&15, row=(lane>>4)*4+r  [m89])
#pragma unroll
    for (int cf = 0; cf < 2; ++cf)
#pragma unroll
        for (int r = 0; r < 4; ++r) {
            const int row = wr * 16 + q * 4 + r;
            const int col = wc * 32 + cf * 16 + rl;
            Yl[row * 132 + col] = acc[cf][r];
        }
    __syncthreads();

    // 2) Y = relu(M_agg + M_self + bias)
    const float bz[4] = {bias[0], bias[1], bias[2], bias[3]};
    const float* Mb = Mself + ((size_t)(b * N_ + r0)) * COLS;
#pragma unroll
    for (int i = 0; i < 2; ++i) {
        const int cell = t + i * 512;     // 1024 cells = 32 rows x 32 d
        const int row = cell >> 5, d = cell & 31;
        const float4 m = *(const float4*)(Mb + (size_t)row * COLS + d * 4);
        const int idx = row * 132 + d * 4;
        float4 y = *(const float4*)(Yl + idx);
        y.x = fmaxf(y.x + m.x + bz[0], 0.f);
        y.y = fmaxf(y.y + m.y + bz[1], 0.f);
        y.z = fmaxf(y.z + m.z + bz[2], 0.f);
        y.w = fmaxf(y.w + m.w + bz[3], 0.f);
        *(float4*)(Yl + idx) = y;
    }
    __syncthreads();

    // 3) G partials: 4 threads per row
    if (t < 128) {
        const int row = t >> 2, qd = t & 3;
        float g[10] = {0,0,0,0,0,0,0,0,0,0};
#pragma unroll
        for (int d = qd * 8; d < qd * 8 + 8; ++d) {
            const float4 y = *(const float4*)(Yl + row * 132 + 4 * d);
            g[0] = fmaf(y.x, y.x, g[0]); g[1] = fmaf(y.x, y.y, g[1]);
            g[2] = fmaf(y.x, y.z, g[2]); g[3] = fmaf(y.x, y.w, g[3]);
            g[4] = fmaf(y.y, y.y, g[4]); g[5] = fmaf(y.y, y.z, g[5]);
            g[6] = fmaf(y.y, y.w, g[6]); g[7] = fmaf(y.z, y.z, g[7]);
            g[8] = fmaf(y.z, y.w, g[8]); g[9] = fmaf(y.w, y.w, g[9]);
        }
        float* gp = Gp + (row * 4 + qd) * 10;
#pragma unroll
        for (int k = 0; k < 10; ++k) gp[k] = g[k];
    }
    __syncthreads();

    // 4) Jacobi eigendecomposition + S = V diag(1/sqrt(l)) V^T  (1 thread/row)
    if (t < 32) {
        float gg[10];
#pragma unroll
        for (int k = 0; k < 10; ++k)
            gg[k] = Gp[(t * 4 + 0) * 10 + k] + Gp[(t * 4 + 1) * 10 + k] +
                    Gp[(t * 4 + 2) * 10 + k] + Gp[(t * 4 + 3) * 10 + k];
        float m[4][4] = {{gg[0], gg[1], gg[2], gg[3]},
                         {gg[1], gg[4], gg[5], gg[6]},
                         {gg[2], gg[5], gg[7], gg[8]},
                         {gg[3], gg[6], gg[8], gg[9]}};
        float v[4][4] = {{1,0,0,0},{0,1,0,0},{0,0,1,0},{0,0,0,1}};
        for (int sweep = 0; sweep < 6; ++sweep) {
#pragma unroll
            for (int p = 0; p < 3; ++p) {
#pragma unroll
                for (int qq = p + 1; qq < 4; ++qq) {
                    const float apq = m[p][qq];
                    if (fabsf(apq) < 1e-28f) continue;
                    const float theta = (m[qq][qq] - m[p][p]) / (2.f * apq);
                    const float tt = copysignf(1.f, theta) /
                        (fabsf(theta) + sqrtf(fmaf(theta, theta, 1.f)));
                    const float c = 1.f / sqrtf(fmaf(tt, tt, 1.f));
                    const float s = tt * c;
#pragma unroll
                    for (int k = 0; k < 4; ++k) {
                        const float mkp = m[k][p], mkq = m[k][qq];
                        m[k][p] = c * mkp - s * mkq;
                        m[k][qq] = s * mkp + c * mkq;
                    }
#pragma unroll
                    for (int k = 0; k < 4; ++k) {
                        const float mpk = m[p][k], mqk = m[qq][k];
                        m[p][k] = c * mpk - s * mqk;
                        m[qq][k] = s * mpk + c * mqk;
                    }
#pragma unroll
                    for (int k = 0; k < 4; ++k) {
                        const float vkp = v[k][p], vkq = v[k][qq];
                        v[k][p] = c * vkp - s * vkq;
                        v[k][qq] = s * vkp + c * vkq;
                    }
                }
            }
        }
        const float lam[4] = {m[0][0], m[1][1], m[2][2], m[3][3]};
        const float lmax = fmaxf(fmaxf(lam[0], lam[1]), fmaxf(lam[2], lam[3]));
        const float lfloor = fmaxf(lmax * 1e-12f, 1e-30f);
        float rlv[4];
#pragma unroll
        for (int k = 0; k < 4; ++k) rlv[k] = 1.f / sqrtf(fmaxf(lam[k], lfloor));
#pragma unroll
        for (int i = 0; i < 4; ++i)
#pragma unroll
            for (int j = 0; j < 4; ++j)
                Sm[t * 16 + i * 4 + j] =
                    v[i][0] * v[j][0] * rlv[0] + v[i][1] * v[j][1] * rlv[1] +
                    v[i][2] * v[j][2] * rlv[2] + v[i][3] * v[j][3] * rlv[3];
    }
    __syncthreads();

    // 5) U_out = Y * S, coalesced store
#pragma unroll
    for (int i = 0; i < 2; ++i) {
        const int cell = t + i * 512;
        const int row = cell >> 5, d = cell & 31;
        const float4 y = *(const float4*)(Yl + row * 132 + 4 * d);
        const float* S = Sm + row * 16;
        float4 o4;
        o4.x = y.x * S[0]  + y.y * S[4]  + y.z * S[8]  + y.w * S[12];
        o4.y = y.x * S[1]  + y.y * S[5]  + y.z * S[9]  + y.w * S[13];
        o4.z = y.x * S[2]  + y.y * S[6]  + y.z * S[10] + y.w * S[14];
        o4.w = y.x * S[3]  + y.y * S[7]  + y.z * S[11] + y.w * S[15];
        *(float4*)(out + ((size_t)(b * N_ + r0 + row)) * COLS + 4 * d) = o4;
    }
}

extern "C" void kernel_launch(void* const* d_in, const int* in_sizes, int n_in,
                              void* d_out, int out_size, void* d_ws, size_t ws_size,
                              hipStream_t stream)
{
    const float* U      = (const float*)d_in[0];
    const float* A      = (const float*)d_in[1];
    const float* Wself  = (const float*)d_in[2];
    const float* Wneigh = (const float*)d_in[3];
    const float* bias   = (const float*)d_in[4];
    float* out = (float*)d_out;

    unsigned short* Btg = (unsigned short*)d_ws;            // [8][128][2048] bf16 = 4MB
    float* Mself = (float*)((char*)d_ws + (size_t)B_ * COLS * N_ * 2);  // 8.4MB f32

    mneigh_t_kernel<<<B_ * (N_ / 32), 256, 0, stream>>>(U, Wneigh, Wself, Btg,
                                                        Mself);
    gemm_proj_kernel<<<B_ * (N_ / BM), 512, 0, stream>>>(A, Btg, Mself, bias,
                                                         out);
}